// Round 2
// baseline (524.115 us; speedup 1.0000x reference)
//
#include <hip/hip_runtime.h>
#include <hip/hip_bf16.h>
#include <stdint.h>

#define PI_F 3.14159265358979f
#define EMBR 0.0275f
#define BATCH 1024
#define DIM 512
#define D2 1024
#define HID 2048
#define NB 30
#define K1 (NB * D2)          // 30720
#define NZ 8                  // r-chunk slices for rtrans GEMM

using short8 = __attribute__((ext_vector_type(8))) short;
using f32x4  = __attribute__((ext_vector_type(4))) float;

__device__ __forceinline__ ushort f2bf(float f) {
  uint32_t u = __builtin_bit_cast(uint32_t, f);
  u += 0x7fffu + ((u >> 16) & 1u);   // RNE
  return (ushort)(u >> 16);
}

// async global->LDS, 16B per lane; LDS dest = wave-uniform base + lane*16
__device__ __forceinline__ void gld_lds16(const void* g, void* l) {
  __builtin_amdgcn_global_load_lds(
      (const __attribute__((address_space(1))) uint32_t*)(uintptr_t)g,
      (__attribute__((address_space(3))) uint32_t*)(uintptr_t)l, 16, 0, 0);
}

// ---------------- fp32 -> bf16 convert (vectorized) ----------------
__global__ __launch_bounds__(256) void cvt4(const float* __restrict__ s,
                                            ushort* __restrict__ d, int n4) {
  int i = blockIdx.x * 256 + threadIdx.x;
  if (i < n4) {
    float4 v = ((const float4*)s)[i];
    ushort4 o;
    o.x = f2bf(v.x); o.y = f2bf(v.y); o.z = f2bf(v.z); o.w = f2bf(v.w);
    ((ushort4*)d)[i] = o;
  }
}

// ---------------- NT GEMM: C[m,n] = sum_k A[m,k] * Bt[n,k] ----------------
// A: M x K row-major (bf16), Bt: N x K row-major (bf16), bias fp32.
// EPI 1: bf16 out = relu(acc + bias[n]);  EPI 2: fp32 out = acc + bias[n]
template <int EPI>
__global__ __launch_bounds__(256, 2) void gemm_nt(
    const ushort* __restrict__ A, const ushort* __restrict__ Bt,
    const float* __restrict__ bias, float* __restrict__ Cf,
    ushort* __restrict__ Cb, int M, int N, int K) {
  __shared__ ushort As[128 * 32];
  __shared__ ushort Bs[128 * 32];
  const int tid  = threadIdx.x;
  const int lane = tid & 63, wave = tid >> 6;
  const int wm = wave >> 1, wn = wave & 1;          // 2x2 wave grid, 64x64/wave
  const int lrow = lane & 15, quad = lane >> 4;
  const int m0 = blockIdx.y * 128, n0 = blockIdx.x * 128;

  f32x4 acc[4][4] = {};

  const int rr = lane >> 2;
  const int eo = (lane & 3) * 8;
  const int c1 = wave, c2 = wave + 4;
  const ushort* Ag1 = A  + (size_t)(m0 + c1 * 16 + rr) * K + eo;
  const ushort* Ag2 = A  + (size_t)(m0 + c2 * 16 + rr) * K + eo;
  const ushort* Bg1 = Bt + (size_t)(n0 + c1 * 16 + rr) * K + eo;
  const ushort* Bg2 = Bt + (size_t)(n0 + c2 * 16 + rr) * K + eo;
  ushort* As1 = As + c1 * 512;
  ushort* As2 = As + c2 * 512;
  ushort* Bs1 = Bs + c1 * 512;
  ushort* Bs2 = Bs + c2 * 512;

  for (int kk = 0; kk < K; kk += 32) {
    __syncthreads();
    gld_lds16(Ag1 + kk, As1);
    gld_lds16(Ag2 + kk, As2);
    gld_lds16(Bg1 + kk, Bs1);
    gld_lds16(Bg2 + kk, Bs2);
    __syncthreads();

    short8 af[4], bq[4];
#pragma unroll
    for (int i = 0; i < 4; ++i) {
      af[i] = *(const short8*)&As[(wm * 64 + i * 16 + lrow) * 32 + quad * 8];
      bq[i] = *(const short8*)&Bs[(wn * 64 + i * 16 + lrow) * 32 + quad * 8];
    }
#pragma unroll
    for (int mi = 0; mi < 4; ++mi)
#pragma unroll
      for (int ni = 0; ni < 4; ++ni)
        acc[mi][ni] = __builtin_amdgcn_mfma_f32_16x16x32_bf16(
            af[mi], bq[ni], acc[mi][ni], 0, 0, 0);
  }

  // D[row][col]: col = lane&15, row = quad*4 + reg  (m89/m91 verified layout)
  const int colBase = n0 + wn * 64;
  const int rowBase = m0 + wm * 64;
#pragma unroll
  for (int mi = 0; mi < 4; ++mi) {
#pragma unroll
    for (int ni = 0; ni < 4; ++ni) {
      const int col  = colBase + ni * 16 + lrow;
      const int row0 = rowBase + mi * 16 + quad * 4;
      const float bv = bias[col];
      if (EPI == 1) {
#pragma unroll
        for (int g = 0; g < 4; ++g)
          Cb[(size_t)(row0 + g) * N + col] = f2bf(fmaxf(acc[mi][ni][g] + bv, 0.f));
      } else {
#pragma unroll
        for (int g = 0; g < 4; ++g)
          Cf[(size_t)(row0 + g) * N + col] = acc[mi][ni][g] + bv;
      }
    }
  }
}

// ------- rtrans GEMM: C1p[z][b][o] = sum_{r in chunk z} att[b,r]*(e @ RB_r)[b,o] -------
// E: 1024x1024 bf16; RBt: D2 x K1 bf16 (RBt[o][r*1024+i]); attb: fp32 B x 32
__global__ __launch_bounds__(256, 2) void gemm_rtrans(
    const ushort* __restrict__ E, const ushort* __restrict__ RBt,
    const float* __restrict__ attb, float* __restrict__ C1p) {
  __shared__ ushort As[128 * 32];
  __shared__ ushort Bs[128 * 32];
  __shared__ float attS[4 * 128];
  const int tid  = threadIdx.x;
  const int lane = tid & 63, wave = tid >> 6;
  const int wm = wave >> 1, wn = wave & 1;
  const int lrow = lane & 15, quad = lane >> 4;
  const int m0 = blockIdx.y * 128, n0 = blockIdx.x * 128;
  const int z = blockIdx.z;
  const int r_start = (z < 7) ? z * 4 : 27;
  const int r_cnt   = (z < 6) ? 4 : 3;

  for (int idx = tid; idx < r_cnt * 128; idx += 256)
    attS[idx] = attb[(size_t)(m0 + (idx & 127)) * 32 + r_start + (idx >> 7)];

  f32x4 acc2[4][4] = {};

  const int rr = lane >> 2;
  const int eo = (lane & 3) * 8;
  const int c1 = wave, c2 = wave + 4;
  const ushort* Ag1 = E + (size_t)(m0 + c1 * 16 + rr) * D2 + eo;
  const ushort* Ag2 = E + (size_t)(m0 + c2 * 16 + rr) * D2 + eo;
  const ushort* Bg1 = RBt + (size_t)(n0 + c1 * 16 + rr) * K1 + eo;
  const ushort* Bg2 = RBt + (size_t)(n0 + c2 * 16 + rr) * K1 + eo;
  ushort* As1 = As + c1 * 512;
  ushort* As2 = As + c2 * 512;
  ushort* Bs1 = Bs + c1 * 512;
  ushort* Bs2 = Bs + c2 * 512;

  for (int rl = 0; rl < r_cnt; ++rl) {
    const size_t rOff = (size_t)(r_start + rl) * D2;
    f32x4 acc[4][4] = {};
    for (int kk = 0; kk < D2; kk += 32) {
      __syncthreads();
      gld_lds16(Ag1 + kk, As1);
      gld_lds16(Ag2 + kk, As2);
      gld_lds16(Bg1 + rOff + kk, Bs1);
      gld_lds16(Bg2 + rOff + kk, Bs2);
      __syncthreads();

      short8 af[4], bq[4];
#pragma unroll
      for (int i = 0; i < 4; ++i) {
        af[i] = *(const short8*)&As[(wm * 64 + i * 16 + lrow) * 32 + quad * 8];
        bq[i] = *(const short8*)&Bs[(wn * 64 + i * 16 + lrow) * 32 + quad * 8];
      }
#pragma unroll
      for (int mi = 0; mi < 4; ++mi)
#pragma unroll
        for (int ni = 0; ni < 4; ++ni)
          acc[mi][ni] = __builtin_amdgcn_mfma_f32_16x16x32_bf16(
              af[mi], bq[ni], acc[mi][ni], 0, 0, 0);
    }
    // scale by att[row, r] and accumulate
#pragma unroll
    for (int mi = 0; mi < 4; ++mi)
#pragma unroll
      for (int g = 0; g < 4; ++g) {
        const float s = attS[rl * 128 + wm * 64 + mi * 16 + quad * 4 + g];
#pragma unroll
        for (int ni = 0; ni < 4; ++ni)
          acc2[mi][ni][g] += s * acc[mi][ni][g];
      }
  }

  float* dst = C1p + (size_t)z * BATCH * D2;
  const int colBase = n0 + wn * 64;
  const int rowBase = m0 + wm * 64;
#pragma unroll
  for (int mi = 0; mi < 4; ++mi)
#pragma unroll
    for (int ni = 0; ni < 4; ++ni) {
      const int col  = colBase + ni * 16 + lrow;
      const int row0 = rowBase + mi * 16 + quad * 4;
#pragma unroll
      for (int g = 0; g < 4; ++g)
        dst[(size_t)(row0 + g) * D2 + col] = acc2[mi][ni][g];
    }
}

// ------- transpose + convert: src fp32 R x C -> dst bf16 C x R -------
__global__ __launch_bounds__(256) void transpose_cvt(
    const float* __restrict__ src, ushort* __restrict__ dst, int R, int C) {
  __shared__ ushort ts[64][68];
  const int c0 = blockIdx.x * 64, r0 = blockIdx.y * 64;
  const int tc = (threadIdx.x & 15) * 4;
  const int tr = threadIdx.x >> 4;  // 0..15
#pragma unroll
  for (int j = 0; j < 4; ++j) {
    const int r = tr + j * 16;
    float4 v = *(const float4*)&src[(size_t)(r0 + r) * C + c0 + tc];
    ushort4 o;
    o.x = f2bf(v.x); o.y = f2bf(v.y); o.z = f2bf(v.z); o.w = f2bf(v.w);
    *(ushort4*)&ts[r][tc] = o;
  }
  __syncthreads();
#pragma unroll
  for (int j = 0; j < 4; ++j) {
    const int c = tr + j * 16;
    ushort4 v;
    v.x = ts[tc + 0][c]; v.y = ts[tc + 1][c];
    v.z = ts[tc + 2][c]; v.w = ts[tc + 3][c];
    *(ushort4*)&dst[(size_t)(c0 + c) * R + r0 + tc] = v;
  }
}

// ------------- prep: att (tanh), e -> bf16, h0 = e + rel angles -------------
__global__ __launch_bounds__(256) void prep(
    const float* __restrict__ axis, const float* __restrict__ argp,
    const int* __restrict__ rel, const float* __restrict__ rel_att,
    const float* __restrict__ rel_axis_e, const float* __restrict__ rel_arg_e,
    float* __restrict__ att_out, ushort* __restrict__ Ebf, ushort* __restrict__ h0) {
  const int b = blockIdx.x, t = threadIdx.x;
  const int ri = rel[b];
  if (t < NB)
    att_out[b * 32 + t] = tanhf(rel_att[ri * NB + t] * (1.f / EMBR)) * PI_F;
  for (int i = t; i < DIM; i += 256) {
    const float ax = axis[(size_t)b * DIM + i];
    const float ag = argp[(size_t)b * DIM + i];
    Ebf[(size_t)b * D2 + i]       = f2bf(ax);
    Ebf[(size_t)b * D2 + DIM + i] = f2bf(ag);
    const float ra = rel_axis_e[(size_t)ri * DIM + i];
    const float rg = rel_arg_e[(size_t)ri * DIM + i];
    h0[(size_t)b * D2 + i] = f2bf(ax + tanhf(ra * (1.f / EMBR)) * PI_F);
    h0[(size_t)b * D2 + DIM + i] =
        f2bf(ag + tanhf(2.f * rg * (1.f / EMBR)) * (PI_F * 0.5f) + PI_F * 0.5f);
  }
}

// ------- reduce slices + att@rel_bias + LayerNorm -> xrt (fp32), Xb row (bf16) -------
__global__ __launch_bounds__(256) void reduce_ln_rt(
    const float* __restrict__ C1p, const float* __restrict__ att,
    const float* __restrict__ rel_bias, float* __restrict__ xf,
    ushort* __restrict__ Xb) {
  const int b = blockIdx.x, t = threadIdx.x;
  __shared__ float attS[NB];
  __shared__ float sa[4], sb[4];
  if (t < NB) attS[t] = att[b * 32 + t];
  __syncthreads();
  float v[4], sum = 0.f, sq = 0.f;
#pragma unroll
  for (int j = 0; j < 4; ++j) {
    const int o = j * 256 + t;
    float acc = 0.f;
#pragma unroll
    for (int s = 0; s < NZ; ++s)
      acc += C1p[((size_t)s * BATCH + b) * D2 + o];
    float bias = 0.f;
    for (int r = 0; r < NB; ++r) bias += attS[r] * rel_bias[r * D2 + o];
    acc += bias;
    v[j] = acc; sum += acc; sq += acc * acc;
  }
  const int lane = t & 63, wv = t >> 6;
  for (int off = 32; off > 0; off >>= 1) {
    sum += __shfl_down(sum, off, 64);
    sq  += __shfl_down(sq, off, 64);
  }
  if (lane == 0) { sa[wv] = sum; sb[wv] = sq; }
  __syncthreads();
  const float S = sa[0] + sa[1] + sa[2] + sa[3];
  const float Q = sb[0] + sb[1] + sb[2] + sb[3];
  const float mean = S / D2;
  const float inv = rsqrtf(fmaxf(Q / D2 - mean * mean, 0.f) + 1e-5f);
#pragma unroll
  for (int j = 0; j < 4; ++j) {
    const int o = j * 256 + t;
    const float y = (v[j] - mean) * inv;
    xf[(size_t)b * D2 + o] = y;
    Xb[(size_t)b * D2 + o] = f2bf(y);
  }
}

// ---------------- row LayerNorm (mlp branch) ----------------
__global__ __launch_bounds__(256) void ln_rows(
    const float* __restrict__ G, float* __restrict__ xf, ushort* __restrict__ Xb) {
  const int b = blockIdx.x, t = threadIdx.x;
  __shared__ float sa[4], sb[4];
  float v[4], sum = 0.f, sq = 0.f;
#pragma unroll
  for (int j = 0; j < 4; ++j) {
    const int o = j * 256 + t;
    v[j] = G[(size_t)b * D2 + o];
    sum += v[j]; sq += v[j] * v[j];
  }
  const int lane = t & 63, wv = t >> 6;
  for (int off = 32; off > 0; off >>= 1) {
    sum += __shfl_down(sum, off, 64);
    sq  += __shfl_down(sq, off, 64);
  }
  if (lane == 0) { sa[wv] = sum; sb[wv] = sq; }
  __syncthreads();
  const float S = sa[0] + sa[1] + sa[2] + sa[3];
  const float Q = sb[0] + sb[1] + sb[2] + sb[3];
  const float mean = S / D2;
  const float inv = rsqrtf(fmaxf(Q / D2 - mean * mean, 0.f) + 1e-5f);
#pragma unroll
  for (int j = 0; j < 4; ++j) {
    const int o = j * 256 + t;
    const float y = (v[j] - mean) * inv;
    xf[(size_t)b * D2 + o] = y;
    Xb[(size_t)b * D2 + o] = f2bf(y);
  }
}

// -------- softmax over 2 branches + merge + final activations -> out (fp32) --------
__global__ __launch_bounds__(256) void fuse_out(
    const float* __restrict__ L, const float* __restrict__ xrt,
    const float* __restrict__ xml, float* __restrict__ out) {
  const int b = blockIdx.x, t = threadIdx.x;
#pragma unroll
  for (int j = 0; j < 4; ++j) {
    const int o = j * 256 + t;
    const float l0 = L[(size_t)b * D2 + o];
    const float l1 = L[(size_t)(BATCH + b) * D2 + o];
    const float w0 = 1.f / (1.f + expf(l1 - l0));
    const float m = w0 * xrt[(size_t)b * D2 + o] +
                    (1.f - w0) * xml[(size_t)b * D2 + o];
    if (o < DIM)
      out[(size_t)b * DIM + o] = tanhf(m) * PI_F;
    else
      out[(size_t)BATCH * DIM + (size_t)b * DIM + (o - DIM)] =
          tanhf(2.f * m) * (PI_F * 0.5f) + PI_F * 0.5f;
  }
}

extern "C" void kernel_launch(void* const* d_in, const int* in_sizes, int n_in,
                              void* d_out, int out_size, void* d_ws, size_t ws_size,
                              hipStream_t stream) {
  (void)in_sizes; (void)n_in; (void)out_size; (void)ws_size;
  const float* s_axis   = (const float*)d_in[0];
  const float* s_arg    = (const float*)d_in[1];
  const int*   rel      = (const int*)d_in[2];
  const float* rel_base = (const float*)d_in[3];
  const float* rel_att  = (const float*)d_in[4];
  const float* rel_bias = (const float*)d_in[5];
  const float* rel_ax_e = (const float*)d_in[6];
  const float* rel_ar_e = (const float*)d_in[7];
  const float* W1 = (const float*)d_in[8];
  const float* b1 = (const float*)d_in[9];
  const float* W2 = (const float*)d_in[10];
  const float* b2 = (const float*)d_in[11];
  const float* W0 = (const float*)d_in[12];
  const float* b0 = (const float*)d_in[13];
  const float* Wa1 = (const float*)d_in[14];
  const float* ba1 = (const float*)d_in[15];
  const float* Wa2 = (const float*)d_in[16];
  const float* ba2 = (const float*)d_in[17];

  char* ws = (char*)d_ws;
  size_t off = 0;
  ushort* RBt  = (ushort*)(ws + off); off += (size_t)K1 * D2 * 2;            // 63 MB
  float*  C1p  = (float*)(ws + off);  off += (size_t)NZ * BATCH * D2 * 4;    // 33.5 MB
  ushort* Ebf  = (ushort*)(ws + off); off += (size_t)BATCH * D2 * 2;         // 2 MB
  ushort* W1b  = (ushort*)(ws + off); off += (size_t)HID * D2 * 2;           // 4 MB
  ushort* W2b  = (ushort*)(ws + off); off += (size_t)HID * HID * 2;          // 8 MB
  ushort* W0b  = (ushort*)(ws + off); off += (size_t)D2 * HID * 2;           // 4 MB
  ushort* Wa1b = (ushort*)(ws + off); off += (size_t)DIM * D2 * 2;           // 1 MB
  ushort* Wa2b = (ushort*)(ws + off); off += (size_t)D2 * DIM * 2;           // 1 MB
  ushort* h0   = (ushort*)(ws + off); off += (size_t)BATCH * D2 * 2;         // 2 MB
  ushort* Xb   = (ushort*)(ws + off); off += (size_t)2 * BATCH * D2 * 2;     // 4 MB
  float*  xrt  = (float*)(ws + off);  off += (size_t)BATCH * D2 * 4;         // 4 MB
  float*  xml  = (float*)(ws + off);  off += (size_t)BATCH * D2 * 4;         // 4 MB
  float*  attb = (float*)(ws + off);  off += (size_t)BATCH * 32 * 4;
  // late buffers alias C1p (dead after reduce_ln_rt); 22 MB <= 33.5 MB
  char* ali = (char*)C1p;
  ushort* H1  = (ushort*)ali; ali += (size_t)BATCH * HID * 2;
  ushort* H2  = (ushort*)ali; ali += (size_t)BATCH * HID * 2;
  float*  G0  = (float*)ali;  ali += (size_t)BATCH * D2 * 4;
  ushort* Aat = (ushort*)ali; ali += (size_t)2 * BATCH * DIM * 2;
  float*  Lg  = (float*)ali;  ali += (size_t)2 * BATCH * D2 * 4;

  // weight fp32->bf16 converts
  cvt4<<<(HID * D2 / 4 + 255) / 256, 256, 0, stream>>>(W1, W1b, HID * D2 / 4);
  cvt4<<<(HID * HID / 4 + 255) / 256, 256, 0, stream>>>(W2, W2b, HID * HID / 4);
  cvt4<<<(D2 * HID / 4 + 255) / 256, 256, 0, stream>>>(W0, W0b, D2 * HID / 4);
  cvt4<<<(DIM * D2 / 4 + 255) / 256, 256, 0, stream>>>(Wa1, Wa1b, DIM * D2 / 4);
  cvt4<<<(D2 * DIM / 4 + 255) / 256, 256, 0, stream>>>(Wa2, Wa2b, D2 * DIM / 4);

  prep<<<BATCH, 256, 0, stream>>>(s_axis, s_arg, rel, rel_att, rel_ax_e,
                                  rel_ar_e, attb, Ebf, h0);
  transpose_cvt<<<dim3(D2 / 64, K1 / 64), 256, 0, stream>>>(rel_base, RBt, K1, D2);
  gemm_rtrans<<<dim3(D2 / 128, BATCH / 128, NZ), 256, 0, stream>>>(
      Ebf, RBt, attb, C1p);
  reduce_ln_rt<<<BATCH, 256, 0, stream>>>(C1p, attb, rel_bias, xrt, Xb);
  gemm_nt<1><<<dim3(HID / 128, BATCH / 128), 256, 0, stream>>>(
      h0, W1b, b1, nullptr, H1, BATCH, HID, D2);
  gemm_nt<1><<<dim3(HID / 128, BATCH / 128), 256, 0, stream>>>(
      H1, W2b, b2, nullptr, H2, BATCH, HID, HID);
  gemm_nt<2><<<dim3(D2 / 128, BATCH / 128), 256, 0, stream>>>(
      H2, W0b, b0, G0, nullptr, BATCH, D2, HID);
  ln_rows<<<BATCH, 256, 0, stream>>>(G0, xml, Xb + (size_t)BATCH * D2);
  gemm_nt<1><<<dim3(DIM / 128, 2 * BATCH / 128), 256, 0, stream>>>(
      Xb, Wa1b, ba1, nullptr, Aat, 2 * BATCH, DIM, D2);
  gemm_nt<2><<<dim3(D2 / 128, 2 * BATCH / 128), 256, 0, stream>>>(
      Aat, Wa2b, ba2, Lg, nullptr, 2 * BATCH, D2, DIM);
  fuse_out<<<BATCH, 256, 0, stream>>>(Lg, xrt, xml, (float*)d_out);
}

// Round 3
// 433.177 us; speedup vs baseline: 1.2099x; 1.2099x over previous
//
#include <hip/hip_runtime.h>
#include <hip/hip_bf16.h>
#include <stdint.h>

#define PI_F 3.14159265358979f
#define EMBR 0.0275f
#define BATCH 1024
#define DIM 512
#define D2 1024
#define HID 2048
#define NB 30
#define K1 (NB * D2)          // 30720
#define NZ 8                  // r-chunk slices for rtrans GEMM

using short8 = __attribute__((ext_vector_type(8))) short;
using f32x4  = __attribute__((ext_vector_type(4))) float;

// s_waitcnt: vmcnt lo [3:0], expcnt [6:4]=7 (ignore), lgkmcnt [11:8]=0xF (ignore), vmcnt hi [15:14]
#define WAITVM(N) __builtin_amdgcn_s_waitcnt(((N) & 0xF) | (((N) >> 4) << 14) | (0x7 << 4) | (0xF << 8))

__device__ __forceinline__ ushort f2bf(float f) {
  uint32_t u = __builtin_bit_cast(uint32_t, f);
  u += 0x7fffu + ((u >> 16) & 1u);   // RNE
  return (ushort)(u >> 16);
}

// async global->LDS, 16B per lane; LDS dest = wave-uniform base + lane*16
__device__ __forceinline__ void gld_lds16(const void* g, void* l) {
  __builtin_amdgcn_global_load_lds(
      (const __attribute__((address_space(1))) uint32_t*)(uintptr_t)g,
      (__attribute__((address_space(3))) uint32_t*)(uintptr_t)l, 16, 0, 0);
}

// ============ mega prep: rel_base transpose+cvt | prep | weight cvts ============
#define TR_BLKS 7680                    // (D2/64=16) x (K1/64=480)
#define PREP_BLKS 1024
#define W1F4 (HID * D2 / 4)             // 524288
#define W2F4 (HID * HID / 4)            // 1048576
#define W0F4 (D2 * HID / 4)             // 524288
#define WA1F4 (DIM * D2 / 4)            // 131072
#define WA2F4 (D2 * DIM / 4)            // 131072
#define CVT_BLKS ((W1F4 + W2F4 + W0F4 + WA1F4 + WA2F4) / 256)  // 9216

__global__ __launch_bounds__(256) void mega_prep(
    const float* __restrict__ rel_base, ushort* __restrict__ RBt,
    const float* __restrict__ axis, const float* __restrict__ argp,
    const int* __restrict__ rel, const float* __restrict__ rel_att,
    const float* __restrict__ rel_ax, const float* __restrict__ rel_ar,
    float* __restrict__ attb, ushort* __restrict__ Ebf, ushort* __restrict__ h0,
    const float* __restrict__ W1, const float* __restrict__ W2,
    const float* __restrict__ W0, const float* __restrict__ Wa1,
    const float* __restrict__ Wa2,
    ushort* __restrict__ W1b, ushort* __restrict__ W2b, ushort* __restrict__ W0b,
    ushort* __restrict__ Wa1b, ushort* __restrict__ Wa2b) {
  __shared__ ushort ts[64][68];
  const int bid = blockIdx.x, t = threadIdx.x;
  if (bid < TR_BLKS) {
    // transpose+cvt of rel_base: src K1 x D2 fp32 -> dst D2 x K1 bf16
    const int c0 = (bid & 15) * 64, r0 = (bid >> 4) * 64;
    const int tc = (t & 15) * 4;
    const int tr = t >> 4;
#pragma unroll
    for (int j = 0; j < 4; ++j) {
      const int r = tr + j * 16;
      float4 v = *(const float4*)&rel_base[(size_t)(r0 + r) * D2 + c0 + tc];
      ushort4 o;
      o.x = f2bf(v.x); o.y = f2bf(v.y); o.z = f2bf(v.z); o.w = f2bf(v.w);
      *(ushort4*)&ts[r][tc] = o;
    }
    __syncthreads();
#pragma unroll
    for (int j = 0; j < 4; ++j) {
      const int c = tr + j * 16;
      ushort4 v;
      v.x = ts[tc + 0][c]; v.y = ts[tc + 1][c];
      v.z = ts[tc + 2][c]; v.w = ts[tc + 3][c];
      *(ushort4*)&RBt[(size_t)(c0 + c) * K1 + r0 + tc] = v;
    }
  } else if (bid < TR_BLKS + PREP_BLKS) {
    const int b = bid - TR_BLKS;
    const int ri = rel[b];
    if (t < NB)
      attb[b * 32 + t] = tanhf(rel_att[ri * NB + t] * (1.f / EMBR)) * PI_F;
    for (int i = t; i < DIM; i += 256) {
      const float ax = axis[(size_t)b * DIM + i];
      const float ag = argp[(size_t)b * DIM + i];
      Ebf[(size_t)b * D2 + i]       = f2bf(ax);
      Ebf[(size_t)b * D2 + DIM + i] = f2bf(ag);
      const float ra = rel_ax[(size_t)ri * DIM + i];
      const float rg = rel_ar[(size_t)ri * DIM + i];
      h0[(size_t)b * D2 + i] = f2bf(ax + tanhf(ra * (1.f / EMBR)) * PI_F);
      h0[(size_t)b * D2 + DIM + i] =
          f2bf(ag + tanhf(2.f * rg * (1.f / EMBR)) * (PI_F * 0.5f) + PI_F * 0.5f);
    }
  } else {
    int i = (bid - TR_BLKS - PREP_BLKS) * 256 + t;
    const float* s; ushort* d;
    if (i < W1F4) { s = W1; d = W1b; }
    else if ((i -= W1F4) < W2F4) { s = W2; d = W2b; }
    else if ((i -= W2F4) < W0F4) { s = W0; d = W0b; }
    else if ((i -= W0F4) < WA1F4) { s = Wa1; d = Wa1b; }
    else { i -= WA1F4; s = Wa2; d = Wa2b; }
    float4 v = ((const float4*)s)[i];
    ushort4 o;
    o.x = f2bf(v.x); o.y = f2bf(v.y); o.z = f2bf(v.z); o.w = f2bf(v.w);
    ((ushort4*)d)[i] = o;
  }
}

// ======= pipelined NT GEMM: C[m,n] = sum_k A[m,k]*Bt[n,k]; depth-3 prefetch =======
// EPI 1: bf16 out = relu(acc + bias[n]);  EPI 2: fp32 out = acc + bias[n]
template <int EPI>
__global__ __launch_bounds__(256, 2) void gemm_nt(
    const ushort* __restrict__ A, const ushort* __restrict__ Bt,
    const float* __restrict__ bias, float* __restrict__ Cf,
    ushort* __restrict__ Cb, int M, int N, int K) {
  __shared__ ushort As[4][128 * 32];
  __shared__ ushort Bs[4][128 * 32];
  const int tid  = threadIdx.x;
  const int lane = tid & 63, wave = tid >> 6;
  const int wm = wave >> 1, wn = wave & 1;
  const int lrow = lane & 15, quad = lane >> 4;
  const int m0 = blockIdx.y * 128, n0 = blockIdx.x * 128;
  const int T = K >> 5;

  const int rr = lane >> 2;
  const int eo = (lane & 3) * 8;
  const int c1 = wave, c2 = wave + 4;
  const ushort* Ag1 = A  + (size_t)(m0 + c1 * 16 + rr) * K + eo;
  const ushort* Ag2 = A  + (size_t)(m0 + c2 * 16 + rr) * K + eo;
  const ushort* Bg1 = Bt + (size_t)(n0 + c1 * 16 + rr) * K + eo;
  const ushort* Bg2 = Bt + (size_t)(n0 + c2 * 16 + rr) * K + eo;

  auto issue = [&](int slot) {
    const int t  = (slot < T - 1) ? slot : T - 1;
    const int bf = slot & 3;
    const int kk = t << 5;
    gld_lds16(Ag1 + kk, &As[bf][c1 * 512]);
    gld_lds16(Ag2 + kk, &As[bf][c2 * 512]);
    gld_lds16(Bg1 + kk, &Bs[bf][c1 * 512]);
    gld_lds16(Bg2 + kk, &Bs[bf][c2 * 512]);
  };

  f32x4 acc[4][4] = {};
  issue(0); issue(1); issue(2);

  for (int t = 0; t < T; ++t) {
    WAITVM(8);                          // tile t's 4 loads done; 2 batches in flight
    __builtin_amdgcn_s_barrier();
    issue(t + 3);
    const ushort* as = As[t & 3];
    const ushort* bs = Bs[t & 3];
    short8 af[4], bq[4];
#pragma unroll
    for (int i = 0; i < 4; ++i) {
      af[i] = *(const short8*)&as[(wm * 64 + i * 16 + lrow) * 32 + quad * 8];
      bq[i] = *(const short8*)&bs[(wn * 64 + i * 16 + lrow) * 32 + quad * 8];
    }
#pragma unroll
    for (int mi = 0; mi < 4; ++mi)
#pragma unroll
      for (int ni = 0; ni < 4; ++ni)
        acc[mi][ni] = __builtin_amdgcn_mfma_f32_16x16x32_bf16(
            af[mi], bq[ni], acc[mi][ni], 0, 0, 0);
  }
  WAITVM(0);                            // drain clamped prefetches before LDS dealloc

  const int colBase = n0 + wn * 64;
  const int rowBase = m0 + wm * 64;
#pragma unroll
  for (int mi = 0; mi < 4; ++mi) {
#pragma unroll
    for (int ni = 0; ni < 4; ++ni) {
      const int col  = colBase + ni * 16 + lrow;
      const int row0 = rowBase + mi * 16 + quad * 4;
      const float bv = bias[col];
      if (EPI == 1) {
#pragma unroll
        for (int g = 0; g < 4; ++g)
          Cb[(size_t)(row0 + g) * N + col] = f2bf(fmaxf(acc[mi][ni][g] + bv, 0.f));
      } else {
#pragma unroll
        for (int g = 0; g < 4; ++g)
          Cf[(size_t)(row0 + g) * N + col] = acc[mi][ni][g] + bv;
      }
    }
  }
}

// ==== pipelined rtrans GEMM: C1p[z] = sum_{r in z} att[:,r] * (e @ RB_r) ====
__global__ __launch_bounds__(256, 2) void gemm_rtrans(
    const ushort* __restrict__ E, const ushort* __restrict__ RBt,
    const float* __restrict__ attb, float* __restrict__ C1p) {
  __shared__ ushort As[4][128 * 32];
  __shared__ ushort Bs[4][128 * 32];
  __shared__ float attS[4 * 128];
  const int tid  = threadIdx.x;
  const int lane = tid & 63, wave = tid >> 6;
  const int wm = wave >> 1, wn = wave & 1;
  const int lrow = lane & 15, quad = lane >> 4;
  const int m0 = blockIdx.y * 128, n0 = blockIdx.x * 128;
  const int z = blockIdx.z;
  const int r_start = (z < 7) ? z * 4 : 27;
  const int r_cnt   = (z < 6) ? 4 : 3;
  const int T = r_cnt << 5;

  for (int idx = tid; idx < r_cnt * 128; idx += 256)
    attS[idx] = attb[(size_t)(m0 + (idx & 127)) * 32 + r_start + (idx >> 7)];

  const int rr = lane >> 2;
  const int eo = (lane & 3) * 8;
  const int c1 = wave, c2 = wave + 4;
  const ushort* Ag1 = E + (size_t)(m0 + c1 * 16 + rr) * D2 + eo;
  const ushort* Ag2 = E + (size_t)(m0 + c2 * 16 + rr) * D2 + eo;
  const ushort* Bg1 = RBt + (size_t)(n0 + c1 * 16 + rr) * K1 + eo;
  const ushort* Bg2 = RBt + (size_t)(n0 + c2 * 16 + rr) * K1 + eo;

  auto issue = [&](int slot) {
    const int t  = (slot < T - 1) ? slot : T - 1;
    const int bf = slot & 3;
    const int ka = (t & 31) << 5;
    const size_t kb = ((size_t)(r_start + (t >> 5)) << 10) + ka;
    gld_lds16(Ag1 + ka, &As[bf][c1 * 512]);
    gld_lds16(Ag2 + ka, &As[bf][c2 * 512]);
    gld_lds16(Bg1 + kb, &Bs[bf][c1 * 512]);
    gld_lds16(Bg2 + kb, &Bs[bf][c2 * 512]);
  };

  f32x4 acc[4][4] = {};
  f32x4 acc2[4][4] = {};
  issue(0); issue(1); issue(2);
  __syncthreads();   // attS visible to all waves (also drains prologue once; cheap)

  for (int t = 0; t < T; ++t) {
    WAITVM(8);
    __builtin_amdgcn_s_barrier();
    issue(t + 3);
    const ushort* as = As[t & 3];
    const ushort* bs = Bs[t & 3];
    short8 af[4], bq[4];
#pragma unroll
    for (int i = 0; i < 4; ++i) {
      af[i] = *(const short8*)&as[(wm * 64 + i * 16 + lrow) * 32 + quad * 8];
      bq[i] = *(const short8*)&bs[(wn * 64 + i * 16 + lrow) * 32 + quad * 8];
    }
#pragma unroll
    for (int mi = 0; mi < 4; ++mi)
#pragma unroll
      for (int ni = 0; ni < 4; ++ni)
        acc[mi][ni] = __builtin_amdgcn_mfma_f32_16x16x32_bf16(
            af[mi], bq[ni], acc[mi][ni], 0, 0, 0);
    if ((t & 31) == 31) {
      const int rl = t >> 5;
#pragma unroll
      for (int mi = 0; mi < 4; ++mi)
#pragma unroll
        for (int g = 0; g < 4; ++g) {
          const float s = attS[rl * 128 + wm * 64 + mi * 16 + quad * 4 + g];
#pragma unroll
          for (int ni = 0; ni < 4; ++ni) {
            acc2[mi][ni][g] += s * acc[mi][ni][g];
            acc[mi][ni][g] = 0.f;
          }
        }
    }
  }
  WAITVM(0);

  float* dst = C1p + (size_t)z * BATCH * D2;
  const int colBase = n0 + wn * 64;
  const int rowBase = m0 + wm * 64;
#pragma unroll
  for (int mi = 0; mi < 4; ++mi)
#pragma unroll
    for (int ni = 0; ni < 4; ++ni) {
      const int col  = colBase + ni * 16 + lrow;
      const int row0 = rowBase + mi * 16 + quad * 4;
#pragma unroll
      for (int g = 0; g < 4; ++g)
        dst[(size_t)(row0 + g) * D2 + col] = acc2[mi][ni][g];
    }
}

// ------- reduce slices + att@rel_bias + LayerNorm -> xrt (fp32), Xb row (bf16) -------
__global__ __launch_bounds__(256) void reduce_ln_rt(
    const float* __restrict__ C1p, const float* __restrict__ att,
    const float* __restrict__ rel_bias, float* __restrict__ xf,
    ushort* __restrict__ Xb) {
  const int b = blockIdx.x, t = threadIdx.x;
  __shared__ float attS[NB];
  __shared__ float sa[4], sb[4];
  if (t < NB) attS[t] = att[b * 32 + t];
  __syncthreads();
  float v[4], sum = 0.f, sq = 0.f;
#pragma unroll
  for (int j = 0; j < 4; ++j) {
    const int o = j * 256 + t;
    float acc = 0.f;
#pragma unroll
    for (int s = 0; s < NZ; ++s)
      acc += C1p[((size_t)s * BATCH + b) * D2 + o];
    float bias = 0.f;
    for (int r = 0; r < NB; ++r) bias += attS[r] * rel_bias[r * D2 + o];
    acc += bias;
    v[j] = acc; sum += acc; sq += acc * acc;
  }
  const int lane = t & 63, wv = t >> 6;
  for (int off = 32; off > 0; off >>= 1) {
    sum += __shfl_down(sum, off, 64);
    sq  += __shfl_down(sq, off, 64);
  }
  if (lane == 0) { sa[wv] = sum; sb[wv] = sq; }
  __syncthreads();
  const float S = sa[0] + sa[1] + sa[2] + sa[3];
  const float Q = sb[0] + sb[1] + sb[2] + sb[3];
  const float mean = S / D2;
  const float inv = rsqrtf(fmaxf(Q / D2 - mean * mean, 0.f) + 1e-5f);
#pragma unroll
  for (int j = 0; j < 4; ++j) {
    const int o = j * 256 + t;
    const float y = (v[j] - mean) * inv;
    xf[(size_t)b * D2 + o] = y;
    Xb[(size_t)b * D2 + o] = f2bf(y);
  }
}

// ---------------- row LayerNorm (mlp branch) ----------------
__global__ __launch_bounds__(256) void ln_rows(
    const float* __restrict__ G, float* __restrict__ xf, ushort* __restrict__ Xb) {
  const int b = blockIdx.x, t = threadIdx.x;
  __shared__ float sa[4], sb[4];
  float v[4], sum = 0.f, sq = 0.f;
#pragma unroll
  for (int j = 0; j < 4; ++j) {
    const int o = j * 256 + t;
    v[j] = G[(size_t)b * D2 + o];
    sum += v[j]; sq += v[j] * v[j];
  }
  const int lane = t & 63, wv = t >> 6;
  for (int off = 32; off > 0; off >>= 1) {
    sum += __shfl_down(sum, off, 64);
    sq  += __shfl_down(sq, off, 64);
  }
  if (lane == 0) { sa[wv] = sum; sb[wv] = sq; }
  __syncthreads();
  const float S = sa[0] + sa[1] + sa[2] + sa[3];
  const float Q = sb[0] + sb[1] + sb[2] + sb[3];
  const float mean = S / D2;
  const float inv = rsqrtf(fmaxf(Q / D2 - mean * mean, 0.f) + 1e-5f);
#pragma unroll
  for (int j = 0; j < 4; ++j) {
    const int o = j * 256 + t;
    const float y = (v[j] - mean) * inv;
    xf[(size_t)b * D2 + o] = y;
    Xb[(size_t)b * D2 + o] = f2bf(y);
  }
}

// -------- softmax over 2 branches + merge + final activations -> out (fp32) --------
__global__ __launch_bounds__(256) void fuse_out(
    const float* __restrict__ L, const float* __restrict__ xrt,
    const float* __restrict__ xml, float* __restrict__ out) {
  const int b = blockIdx.x, t = threadIdx.x;
#pragma unroll
  for (int j = 0; j < 4; ++j) {
    const int o = j * 256 + t;
    const float l0 = L[(size_t)b * D2 + o];
    const float l1 = L[(size_t)(BATCH + b) * D2 + o];
    const float w0 = 1.f / (1.f + expf(l1 - l0));
    const float m = w0 * xrt[(size_t)b * D2 + o] +
                    (1.f - w0) * xml[(size_t)b * D2 + o];
    if (o < DIM)
      out[(size_t)b * DIM + o] = tanhf(m) * PI_F;
    else
      out[(size_t)BATCH * DIM + (size_t)b * DIM + (o - DIM)] =
          tanhf(2.f * m) * (PI_F * 0.5f) + PI_F * 0.5f;
  }
}

extern "C" void kernel_launch(void* const* d_in, const int* in_sizes, int n_in,
                              void* d_out, int out_size, void* d_ws, size_t ws_size,
                              hipStream_t stream) {
  (void)in_sizes; (void)n_in; (void)out_size; (void)ws_size;
  const float* s_axis   = (const float*)d_in[0];
  const float* s_arg    = (const float*)d_in[1];
  const int*   rel      = (const int*)d_in[2];
  const float* rel_base = (const float*)d_in[3];
  const float* rel_att  = (const float*)d_in[4];
  const float* rel_bias = (const float*)d_in[5];
  const float* rel_ax_e = (const float*)d_in[6];
  const float* rel_ar_e = (const float*)d_in[7];
  const float* W1 = (const float*)d_in[8];
  const float* b1 = (const float*)d_in[9];
  const float* W2 = (const float*)d_in[10];
  const float* b2 = (const float*)d_in[11];
  const float* W0 = (const float*)d_in[12];
  const float* b0 = (const float*)d_in[13];
  const float* Wa1 = (const float*)d_in[14];
  const float* ba1 = (const float*)d_in[15];
  const float* Wa2 = (const float*)d_in[16];
  const float* ba2 = (const float*)d_in[17];

  char* ws = (char*)d_ws;
  size_t off = 0;
  ushort* RBt  = (ushort*)(ws + off); off += (size_t)K1 * D2 * 2;            // 63 MB
  float*  C1p  = (float*)(ws + off);  off += (size_t)NZ * BATCH * D2 * 4;    // 33.5 MB
  ushort* Ebf  = (ushort*)(ws + off); off += (size_t)BATCH * D2 * 2;
  ushort* W1b  = (ushort*)(ws + off); off += (size_t)HID * D2 * 2;
  ushort* W2b  = (ushort*)(ws + off); off += (size_t)HID * HID * 2;
  ushort* W0b  = (ushort*)(ws + off); off += (size_t)D2 * HID * 2;
  ushort* Wa1b = (ushort*)(ws + off); off += (size_t)DIM * D2 * 2;
  ushort* Wa2b = (ushort*)(ws + off); off += (size_t)D2 * DIM * 2;
  ushort* h0   = (ushort*)(ws + off); off += (size_t)BATCH * D2 * 2;
  ushort* Xb   = (ushort*)(ws + off); off += (size_t)2 * BATCH * D2 * 2;
  float*  xrt  = (float*)(ws + off);  off += (size_t)BATCH * D2 * 4;
  float*  xml  = (float*)(ws + off);  off += (size_t)BATCH * D2 * 4;
  float*  attb = (float*)(ws + off);  off += (size_t)BATCH * 32 * 4;
  // late buffers alias C1p (dead after reduce_ln_rt); 22 MB <= 33.5 MB
  char* ali = (char*)C1p;
  ushort* H1  = (ushort*)ali; ali += (size_t)BATCH * HID * 2;
  ushort* H2  = (ushort*)ali; ali += (size_t)BATCH * HID * 2;
  float*  G0  = (float*)ali;  ali += (size_t)BATCH * D2 * 4;
  ushort* Aat = (ushort*)ali; ali += (size_t)2 * BATCH * DIM * 2;
  float*  Lg  = (float*)ali;  ali += (size_t)2 * BATCH * D2 * 4;

  mega_prep<<<TR_BLKS + PREP_BLKS + CVT_BLKS, 256, 0, stream>>>(
      rel_base, RBt, s_axis, s_arg, rel, rel_att, rel_ax_e, rel_ar_e,
      attb, Ebf, h0, W1, W2, W0, Wa1, Wa2, W1b, W2b, W0b, Wa1b, Wa2b);
  gemm_rtrans<<<dim3(D2 / 128, BATCH / 128, NZ), 256, 0, stream>>>(
      Ebf, RBt, attb, C1p);
  reduce_ln_rt<<<BATCH, 256, 0, stream>>>(C1p, attb, rel_bias, xrt, Xb);
  gemm_nt<1><<<dim3(HID / 128, BATCH / 128), 256, 0, stream>>>(
      h0, W1b, b1, nullptr, H1, BATCH, HID, D2);
  gemm_nt<1><<<dim3(HID / 128, BATCH / 128), 256, 0, stream>>>(
      H1, W2b, b2, nullptr, H2, BATCH, HID, HID);
  gemm_nt<2><<<dim3(D2 / 128, BATCH / 128), 256, 0, stream>>>(
      H2, W0b, b0, G0, nullptr, BATCH, D2, HID);
  ln_rows<<<BATCH, 256, 0, stream>>>(G0, xml, Xb + (size_t)BATCH * D2);
  gemm_nt<1><<<dim3(DIM / 128, 2 * BATCH / 128), 256, 0, stream>>>(
      Xb, Wa1b, ba1, nullptr, Aat, 2 * BATCH, DIM, D2);
  gemm_nt<2><<<dim3(D2 / 128, 2 * BATCH / 128), 256, 0, stream>>>(
      Aat, Wa2b, ba2, Lg, nullptr, 2 * BATCH, D2, DIM);
  fuse_out<<<BATCH, 256, 0, stream>>>(Lg, xrt, xml, (float*)d_out);
}